// Round 7
// baseline (82.398 us; speedup 1.0000x reference)
//
#include <hip/hip_runtime.h>

// ROI max pooling, round 7: 2D RMQ tables + TEMPORAL chunk phasing for L2.
// features: [1,512,64,64] fp32  proposals: [2000,4] fp32  out: [2000,512,7,7] fp32
//
// Tables per 64-channel chunk: M[kh][kw][h][w][64c], kh,kw in {0,1}. 4 tables
// x 1 MB = 4 MB = one XCD L2. Round 6 mapped chunk = blockIdx&7 assuming
// round-robin XCD dispatch pins each chunk to one XCD L2 -- timing says that
// failed (reads ran at L3 speed). Round 7: chunk = blockIdx/2000, so the
// dispatch wavefront processes one chunk at a time; the live working set is
// ~4 MB and fits EVERY XCD's L2 regardless of block->XCD mapping.
// Any bin (lens 1..5) = max of (2..3)x(2..3) statically-addressed lookups,
// zero runtime loops; redundant duplicate lookups are back-to-back L1 hits.
// Output via LDS stage + contiguous nontemporal float2 (full-line, no L2 alloc).

#define NCH   512
#define FH    64
#define FW    64
#define NPROP 2000
#define ROI   7
#define OUT_PER_PROP (NCH * ROI * ROI)       // 25088
#define NCHUNK 8
#define CCH    64                            // channels per chunk
#define TABF   (FH * FW * CCH)               // 262144 floats = 1 MB per table
#define CHUNK_F (4 * TABF)                   // M00|M01|M10|M11
#define TAB_BYTES ((size_t)NCHUNK * CHUNK_F * 4)   // 32 MB
#define ROWF2  (FW * CCH / 2)                // 2048 float2 per (table,h) row

__global__ __launch_bounds__(256) void prep2d_kernel(
    const float* __restrict__ f,   // [512][64][64]
    float* __restrict__ ws)
{
    __shared__ float tA[64][65];             // row h   [c_local][w]
    __shared__ float tB[64][65];             // row h+1 (clamped)
    const int b  = blockIdx.x;
    const int q  = b & 7;                    // chunk
    const int h  = b >> 3;
    const int h2 = min(h + 1, FH - 1);
    const int c0 = q * CCH;
    const int tw = threadIdx.x & 63;
    const int tg = threadIdx.x >> 6;
#pragma unroll
    for (int r = 0; r < 16; ++r) {
        const int cl = r * 4 + tg;
        tA[cl][tw] = f[(size_t)(c0 + cl) * (FH * FW) + h  * FW + tw];
        tB[cl][tw] = f[(size_t)(c0 + cl) * (FH * FW) + h2 * FW + tw];
    }
    __syncthreads();
    float* __restrict__ T = ws + (size_t)q * CHUNK_F + h * (FW * CCH);
#pragma unroll
    for (int r = 0; r < 16; ++r) {
        const int wl = r * 4 + tg;
        const int w1 = min(wl + 1, FW - 1);
        const float a0 = tA[tw][wl], a1 = tA[tw][w1];
        const float b0 = tB[tw][wl], b1 = tB[tw][w1];
        const float m01 = fmaxf(a0, a1);                 // 1h x 2w
        const float m10 = fmaxf(a0, b0);                 // 2h x 1w
        const float m11 = fmaxf(m01, fmaxf(b0, b1));     // 2h x 2w
        const int o = wl * CCH + tw;
        T[o]            = a0;
        T[TABF + o]     = m01;
        T[2 * TABF + o] = m10;
        T[3 * TABF + o] = m11;
    }
}

__device__ __forceinline__ void compute_bins(
    const float* __restrict__ props, int n,
    int* s_hs, int* s_he, int* s_ws, int* s_we)
{
    if (threadIdx.x < ROI) {
        const int i = threadIdx.x;
        const int x1 = (int)floorf(props[n * 4 + 0] * 0.0625f);
        const int y1 = (int)floorf(props[n * 4 + 1] * 0.0625f);
        const int x2 = (int)floorf(props[n * 4 + 2] * 0.0625f);
        const int y2 = (int)floorf(props[n * 4 + 3] * 0.0625f);
        const int Lh = y2 - y1;
        const int Lw = x2 - x1;
        s_hs[i] = max(y1 + (i * Lh) / ROI, 0);
        s_he[i] = min(y1 + ((i + 1) * Lh + (ROI - 1)) / ROI, FH);
        s_ws[i] = max(x1 + (i * Lw) / ROI, 0);
        s_we[i] = min(x1 + ((i + 1) * Lw + (ROI - 1)) / ROI, FW);
    }
}

// All loads statically addressed; H3/W3 add the rare 3rd lookup (len==5 dims).
template<bool H3, bool W3>
__device__ __forceinline__ void accum2d(
    const float2* __restrict__ t2,
    int baseA, int baseB, int baseC,                       // per-thread f2 offsets
    const int sA[ROI], const int sB[ROI], const int sC[ROI],  // per-j uniform offsets
    float m0[ROI], float m1[ROI])
{
#pragma unroll
    for (int j = 0; j < ROI; ++j) {
        const float2 uAA = t2[(size_t)(baseA + sA[j])];
        const float2 uAB = t2[(size_t)(baseA + sB[j])];
        const float2 uBA = t2[(size_t)(baseB + sA[j])];
        const float2 uBB = t2[(size_t)(baseB + sB[j])];
        float x0 = fmaxf(fmaxf(uAA.x, uAB.x), fmaxf(uBA.x, uBB.x));
        float x1 = fmaxf(fmaxf(uAA.y, uAB.y), fmaxf(uBA.y, uBB.y));
        if (W3) {
            const float2 uAC = t2[(size_t)(baseA + sC[j])];
            const float2 uBC = t2[(size_t)(baseB + sC[j])];
            x0 = fmaxf(x0, fmaxf(uAC.x, uBC.x));
            x1 = fmaxf(x1, fmaxf(uAC.y, uBC.y));
        }
        if (H3) {
            const float2 uCA = t2[(size_t)(baseC + sA[j])];
            const float2 uCB = t2[(size_t)(baseC + sB[j])];
            x0 = fmaxf(x0, fmaxf(uCA.x, uCB.x));
            x1 = fmaxf(x1, fmaxf(uCA.y, uCB.y));
            if (W3) {
                const float2 uCC = t2[(size_t)(baseC + sC[j])];
                x0 = fmaxf(x0, uCC.x);
                x1 = fmaxf(x1, uCC.y);
            }
        }
        m0[j] = x0;
        m1[j] = x1;
    }
}

__global__ __launch_bounds__(256) void roipool_2d_kernel(
    const float* __restrict__ tabs,
    const float* __restrict__ props,
    float* __restrict__ out)
{
    const int b = blockIdx.x;
    const int q = b / NPROP;       // chunk varies SLOWLY -> live set = 4 MB, L2-fit
    const int n = b - q * NPROP;

    __shared__ int s_hs[ROI], s_he[ROI], s_ws[ROI], s_we[ROI];
    __shared__ float s_stage[CCH * 49];      // 12544 B
    compute_bins(props, n, s_hs, s_he, s_ws, s_we);
    __syncthreads();

    // per-w-bin lookup offsets (block-uniform -> SGPR), in float2 units:
    // s = kw*(TABF/2) + w*(CCH/2)
    int sA[ROI], sB[ROI], sC[ROI];
    bool w5 = false, h5 = false;
#pragma unroll
    for (int j = 0; j < ROI; ++j) {
        const int wsj = __builtin_amdgcn_readfirstlane(s_ws[j]);
        const int wej = __builtin_amdgcn_readfirstlane(s_we[j]);
        const int len = wej - wsj;                        // 1..5
        const int kwo = (len >= 2) ? (TABF / 2) : 0;
        const int wB  = (len >= 3) ? (wej - 2) : wsj;
        const int wC  = (len == 5) ? (wsj + 2) : wsj;
        sA[j] = kwo + wsj * (CCH / 2);
        sB[j] = kwo + wB  * (CCH / 2);
        sC[j] = kwo + wC  * (CCH / 2);
        w5 = w5 || (len == 5);
        const int hl = __builtin_amdgcn_readfirstlane(s_he[j]) -
                       __builtin_amdgcn_readfirstlane(s_hs[j]);
        h5 = h5 || (hl == 5);
    }

    // per-thread: slot -> h-bin; h params read from LDS (dynamic bi -> LDS, not
    // a local array: rule #20), kept in VGPRs.
    const int slot = threadIdx.x >> 5;       // 0..7
    const int bi   = min(slot, 6);           // slot 7 duplicates bi 6 (no store)
    const int c2   = threadIdx.x & 31;       // float2 channel within chunk
    const int hsb  = s_hs[bi];
    const int heb  = s_he[bi];
    const int hlen = heb - hsb;
    const int khoff = (hlen >= 2) ? TABF : 0;            // kh*2 tables, f2 units
    const int hB   = (hlen >= 3) ? (heb - 2) : hsb;
    const int hC   = (hlen == 5) ? (hsb + 2) : hsb;

    const float2* __restrict__ t2 = (const float2*)tabs + (size_t)q * (CHUNK_F / 2);
    const int baseA = khoff + hsb * ROWF2 + c2;
    const int baseB = khoff + hB  * ROWF2 + c2;
    const int baseC = khoff + hC  * ROWF2 + c2;

    float m0[ROI], m1[ROI];
    if (h5) {
        if (w5) accum2d<true,  true >(t2, baseA, baseB, baseC, sA, sB, sC, m0, m1);
        else    accum2d<true,  false>(t2, baseA, baseB, baseC, sA, sB, sC, m0, m1);
    } else {
        if (w5) accum2d<false, true >(t2, baseA, baseB, baseC, sA, sB, sC, m0, m1);
        else    accum2d<false, false>(t2, baseA, baseB, baseC, sA, sB, sC, m0, m1);
    }

    if (slot < 7) {
#pragma unroll
        for (int j = 0; j < ROI; ++j) {
            s_stage[(2 * c2)     * 49 + bi * 7 + j] = m0[j];
            s_stage[(2 * c2 + 1) * 49 + bi * 7 + j] = m1[j];
        }
    }
    __syncthreads();

    // contiguous 12544 B span for (n, chunk q): full-line nontemporal stores
    double* __restrict__ dsto = (double*)(out + (size_t)n * OUT_PER_PROP + q * (CCH * 49));
    const double* __restrict__ srco = (const double*)s_stage;
    for (int i = threadIdx.x; i < (CCH * 49 / 2); i += 256)   // 1568 float2
        __builtin_nontemporal_store(srco[i], dsto + i);
}

// Fallback if ws too small: direct divergent kernel (correct, slower).
__global__ __launch_bounds__(256) void roipool_direct_kernel(
    const float* __restrict__ feats,
    const float* __restrict__ props,
    float* __restrict__ out)
{
    const int n = blockIdx.x;
    __shared__ int s_hs[ROI], s_he[ROI], s_ws[ROI], s_we[ROI];
    compute_bins(props, n, s_hs, s_he, s_ws, s_we);
    __syncthreads();
    const float NEG = -3.402823466e+38f;
    const int base = blockIdx.y * (256 * ROI);
    float* outn = out + (size_t)n * OUT_PER_PROP;
#pragma unroll
    for (int k = 0; k < ROI; ++k) {
        const int idx = base + k * 256 + threadIdx.x;
        const int c   = idx / (ROI * ROI);
        const int bin = idx - c * (ROI * ROI);
        const int bi  = bin / ROI;
        const int bj  = bin - bi * ROI;
        float acc = NEG;
        for (int h = s_hs[bi]; h < s_he[bi]; ++h)
            for (int w = s_ws[bj]; w < s_we[bj]; ++w)
                acc = fmaxf(acc, feats[(size_t)c * (FH * FW) + h * FW + w]);
        outn[idx] = acc;
    }
}

extern "C" void kernel_launch(void* const* d_in, const int* in_sizes, int n_in,
                              void* d_out, int out_size, void* d_ws, size_t ws_size,
                              hipStream_t stream) {
    const float* feats = (const float*)d_in[0];
    const float* props = (const float*)d_in[1];
    float* out = (float*)d_out;
    float* ws  = (float*)d_ws;

    if (ws_size >= TAB_BYTES) {
        prep2d_kernel<<<dim3(FH * NCHUNK), 256, 0, stream>>>(feats, ws);
        roipool_2d_kernel<<<dim3(NPROP * NCHUNK), 256, 0, stream>>>(ws, props, out);
    } else {
        roipool_direct_kernel<<<dim3(NPROP, ROI * 2), 256, 0, stream>>>(feats, props, out);
    }
}

// Round 9
// 72.404 us; speedup vs baseline: 1.1380x; 1.1380x over previous
//
#include <hip/hip_runtime.h>

// ROI max pooling, round 8b: 2D RMQ tables, single 28-deep load burst per
// thread (VGPR budget raised to 128), masked duplicate slot, 16B NT stores.
// (8a failed to compile: __builtin_nontemporal_store rejects HIP float4;
//  use a clang ext_vector_type(4) alias instead.)
// features: [1,512,64,64] fp32  proposals: [2000,4] fp32  out: [2000,512,7,7] fp32
//
// Tables per 64-channel chunk: M[kh][kw][h][w][64c], kh,kw in {0,1}. Any bin
// (lens 1..5) = max of (2..3)x(2..3) statically-addressed lookups, no runtime
// loops. Round-5 counters showed VGPR_Count=64 -> the 28-load burst was being
// split into ~4 waited batches; __launch_bounds__(256,4) + load-all-then-reduce
// restores a single deep burst (realized occupancy was ~9 waves/CU < new cap).

#define NCH   512
#define FH    64
#define FW    64
#define NPROP 2000
#define ROI   7
#define OUT_PER_PROP (NCH * ROI * ROI)       // 25088
#define NCHUNK 8
#define CCH    64                            // channels per chunk
#define TABF   (FH * FW * CCH)               // 262144 floats = 1 MB per table
#define CHUNK_F (4 * TABF)                   // M00|M01|M10|M11
#define TAB_BYTES ((size_t)NCHUNK * CHUNK_F * 4)   // 32 MB
#define ROWF2  (FW * CCH / 2)                // 2048 float2 per (table,h) row

typedef float floatx4 __attribute__((ext_vector_type(4)));

__global__ __launch_bounds__(256) void prep2d_kernel(
    const float* __restrict__ f,   // [512][64][64]
    float* __restrict__ ws)
{
    __shared__ float tA[64][65];             // row h   [c_local][w]
    __shared__ float tB[64][65];             // row h+1 (clamped)
    const int b  = blockIdx.x;
    const int q  = b & 7;                    // chunk
    const int h  = b >> 3;
    const int h2 = min(h + 1, FH - 1);
    const int c0 = q * CCH;
    const int tw = threadIdx.x & 63;
    const int tg = threadIdx.x >> 6;
#pragma unroll
    for (int r = 0; r < 16; ++r) {
        const int cl = r * 4 + tg;
        tA[cl][tw] = f[(size_t)(c0 + cl) * (FH * FW) + h  * FW + tw];
        tB[cl][tw] = f[(size_t)(c0 + cl) * (FH * FW) + h2 * FW + tw];
    }
    __syncthreads();
    float* __restrict__ T = ws + (size_t)q * CHUNK_F + h * (FW * CCH);
#pragma unroll
    for (int r = 0; r < 16; ++r) {
        const int wl = r * 4 + tg;
        const int w1 = min(wl + 1, FW - 1);
        const float a0 = tA[tw][wl], a1 = tA[tw][w1];
        const float b0 = tB[tw][wl], b1 = tB[tw][w1];
        const float m01 = fmaxf(a0, a1);                 // 1h x 2w
        const float m10 = fmaxf(a0, b0);                 // 2h x 1w
        const float m11 = fmaxf(m01, fmaxf(b0, b1));     // 2h x 2w
        const int o = wl * CCH + tw;
        T[o]            = a0;
        T[TABF + o]     = m01;
        T[2 * TABF + o] = m10;
        T[3 * TABF + o] = m11;
    }
}

__device__ __forceinline__ void compute_bins(
    const float* __restrict__ props, int n,
    int* s_hs, int* s_he, int* s_ws, int* s_we)
{
    if (threadIdx.x < ROI) {
        const int i = threadIdx.x;
        const int x1 = (int)floorf(props[n * 4 + 0] * 0.0625f);
        const int y1 = (int)floorf(props[n * 4 + 1] * 0.0625f);
        const int x2 = (int)floorf(props[n * 4 + 2] * 0.0625f);
        const int y2 = (int)floorf(props[n * 4 + 3] * 0.0625f);
        const int Lh = y2 - y1;
        const int Lw = x2 - x1;
        s_hs[i] = max(y1 + (i * Lh) / ROI, 0);
        s_he[i] = min(y1 + ((i + 1) * Lh + (ROI - 1)) / ROI, FH);
        s_ws[i] = max(x1 + (i * Lw) / ROI, 0);
        s_we[i] = min(x1 + ((i + 1) * Lw + (ROI - 1)) / ROI, FW);
    }
}

// Load ALL lookups into statically-indexed register arrays (one deep burst,
// one vmcnt wait), then reduce. H3/W3 add the rare len==5 third lookup.
template<bool H3, bool W3>
__device__ __forceinline__ void accum2d(
    const float2* __restrict__ t2,
    int baseA, int baseB, int baseC,                       // per-thread f2 offsets
    const int sA[ROI], const int sB[ROI], const int sC[ROI],  // per-j uniform offsets
    float m0[ROI], float m1[ROI])
{
    float2 rAA[ROI], rAB[ROI], rBA[ROI], rBB[ROI];
#pragma unroll
    for (int j = 0; j < ROI; ++j) {
        rAA[j] = t2[(size_t)(baseA + sA[j])];
        rAB[j] = t2[(size_t)(baseA + sB[j])];
        rBA[j] = t2[(size_t)(baseB + sA[j])];
        rBB[j] = t2[(size_t)(baseB + sB[j])];
    }
#pragma unroll
    for (int j = 0; j < ROI; ++j) {
        float x0 = fmaxf(fmaxf(rAA[j].x, rAB[j].x), fmaxf(rBA[j].x, rBB[j].x));
        float x1 = fmaxf(fmaxf(rAA[j].y, rAB[j].y), fmaxf(rBA[j].y, rBB[j].y));
        if (W3) {
            const float2 uAC = t2[(size_t)(baseA + sC[j])];
            const float2 uBC = t2[(size_t)(baseB + sC[j])];
            x0 = fmaxf(x0, fmaxf(uAC.x, uBC.x));
            x1 = fmaxf(x1, fmaxf(uAC.y, uBC.y));
        }
        if (H3) {
            const float2 uCA = t2[(size_t)(baseC + sA[j])];
            const float2 uCB = t2[(size_t)(baseC + sB[j])];
            x0 = fmaxf(x0, fmaxf(uCA.x, uCB.x));
            x1 = fmaxf(x1, fmaxf(uCA.y, uCB.y));
            if (W3) {
                const float2 uCC = t2[(size_t)(baseC + sC[j])];
                x0 = fmaxf(x0, uCC.x);
                x1 = fmaxf(x1, uCC.y);
            }
        }
        m0[j] = x0;
        m1[j] = x1;
    }
}

__global__ __launch_bounds__(256, 4) void roipool_2d_kernel(
    const float* __restrict__ tabs,
    const float* __restrict__ props,
    float* __restrict__ out)
{
    const int b = blockIdx.x;
    const int q = b & 7;           // chunk (round-6 mapping: best measured)
    const int n = b >> 3;

    __shared__ int s_hs[ROI], s_he[ROI], s_ws[ROI], s_we[ROI];
    __shared__ __align__(16) float s_stage[CCH * 49];      // 12544 B
    compute_bins(props, n, s_hs, s_he, s_ws, s_we);
    __syncthreads();

    // per-w-bin lookup offsets (block-uniform -> SGPR), in float2 units:
    // s = kw*(TABF/2) + w*(CCH/2)
    int sA[ROI], sB[ROI], sC[ROI];
    bool w5 = false, h5 = false;
#pragma unroll
    for (int j = 0; j < ROI; ++j) {
        const int wsj = __builtin_amdgcn_readfirstlane(s_ws[j]);
        const int wej = __builtin_amdgcn_readfirstlane(s_we[j]);
        const int len = wej - wsj;                        // 1..5
        const int kwo = (len >= 2) ? (TABF / 2) : 0;
        const int wB  = (len >= 3) ? (wej - 2) : wsj;
        const int wC  = (len == 5) ? (wsj + 2) : wsj;
        sA[j] = kwo + wsj * (CCH / 2);
        sB[j] = kwo + wB  * (CCH / 2);
        sC[j] = kwo + wC  * (CCH / 2);
        w5 = w5 || (len == 5);
        const int hl = __builtin_amdgcn_readfirstlane(s_he[j]) -
                       __builtin_amdgcn_readfirstlane(s_hs[j]);
        h5 = h5 || (hl == 5);
    }

    const int slot = threadIdx.x >> 5;       // 0..7; slot 7 is idle (masked)
    const int bi   = min(slot, 6);
    const int c2   = threadIdx.x & 31;       // float2 channel within chunk

    if (slot < 7) {
        const int hsb  = s_hs[bi];
        const int heb  = s_he[bi];
        const int hlen = heb - hsb;
        const int khoff = (hlen >= 2) ? TABF : 0;        // kh tables, f2 units
        const int hB   = (hlen >= 3) ? (heb - 2) : hsb;
        const int hC   = (hlen == 5) ? (hsb + 2) : hsb;

        const float2* __restrict__ t2 = (const float2*)tabs + (size_t)q * (CHUNK_F / 2);
        const int baseA = khoff + hsb * ROWF2 + c2;
        const int baseB = khoff + hB  * ROWF2 + c2;
        const int baseC = khoff + hC  * ROWF2 + c2;

        float m0[ROI], m1[ROI];
        if (h5) {
            if (w5) accum2d<true,  true >(t2, baseA, baseB, baseC, sA, sB, sC, m0, m1);
            else    accum2d<true,  false>(t2, baseA, baseB, baseC, sA, sB, sC, m0, m1);
        } else {
            if (w5) accum2d<false, true >(t2, baseA, baseB, baseC, sA, sB, sC, m0, m1);
            else    accum2d<false, false>(t2, baseA, baseB, baseC, sA, sB, sC, m0, m1);
        }

#pragma unroll
        for (int j = 0; j < ROI; ++j) {
            s_stage[(2 * c2)     * 49 + bi * 7 + j] = m0[j];
            s_stage[(2 * c2 + 1) * 49 + bi * 7 + j] = m1[j];
        }
    }
    __syncthreads();

    // contiguous 12544 B span for (n, chunk q): full-line nontemporal 16B stores
    floatx4* __restrict__ dsto = (floatx4*)(out + (size_t)n * OUT_PER_PROP + q * (CCH * 49));
    const floatx4* __restrict__ srco = (const floatx4*)s_stage;
    for (int i = threadIdx.x; i < (CCH * 49 / 4); i += 256)   // 784 x 16B
        __builtin_nontemporal_store(srco[i], dsto + i);
}

// Fallback if ws too small: direct divergent kernel (correct, slower).
__global__ __launch_bounds__(256) void roipool_direct_kernel(
    const float* __restrict__ feats,
    const float* __restrict__ props,
    float* __restrict__ out)
{
    const int n = blockIdx.x;
    __shared__ int s_hs[ROI], s_he[ROI], s_ws[ROI], s_we[ROI];
    compute_bins(props, n, s_hs, s_he, s_ws, s_we);
    __syncthreads();
    const float NEG = -3.402823466e+38f;
    const int base = blockIdx.y * (256 * ROI);
    float* outn = out + (size_t)n * OUT_PER_PROP;
#pragma unroll
    for (int k = 0; k < ROI; ++k) {
        const int idx = base + k * 256 + threadIdx.x;
        const int c   = idx / (ROI * ROI);
        const int bin = idx - c * (ROI * ROI);
        const int bi  = bin / ROI;
        const int bj  = bin - bi * ROI;
        float acc = NEG;
        for (int h = s_hs[bi]; h < s_he[bi]; ++h)
            for (int w = s_ws[bj]; w < s_we[bj]; ++w)
                acc = fmaxf(acc, feats[(size_t)c * (FH * FW) + h * FW + w]);
        outn[idx] = acc;
    }
}

extern "C" void kernel_launch(void* const* d_in, const int* in_sizes, int n_in,
                              void* d_out, int out_size, void* d_ws, size_t ws_size,
                              hipStream_t stream) {
    const float* feats = (const float*)d_in[0];
    const float* props = (const float*)d_in[1];
    float* out = (float*)d_out;
    float* ws  = (float*)d_ws;

    if (ws_size >= TAB_BYTES) {
        prep2d_kernel<<<dim3(FH * NCHUNK), 256, 0, stream>>>(feats, ws);
        roipool_2d_kernel<<<dim3(NPROP * NCHUNK), 256, 0, stream>>>(ws, props, out);
    } else {
        roipool_direct_kernel<<<dim3(NPROP, ROI * 2), 256, 0, stream>>>(feats, props, out);
    }
}